// Round 17
// baseline (338.220 us; speedup 1.0000x reference)
//
#include <hip/hip_runtime.h>
#include <hip/hip_bf16.h>

#define BB 128
#define NN 512
#define NR 1024   // y8 rows per batch: positives [0,P), negatives [512,512+Q)
#define DD 1024
#define MARGIN 0.3f

typedef __attribute__((ext_vector_type(8))) short bf16x8;
typedef __attribute__((ext_vector_type(4))) float f32x4;
typedef __attribute__((ext_vector_type(8))) unsigned short ushort8;
typedef long i64f8;   // 8 x fp8 (2 VGPR) MFMA operand

__device__ __forceinline__ unsigned short f2bf(float f) {
    unsigned int u = __float_as_uint(f);
    u += 0x7FFFu + ((u >> 16) & 1u);
    return (unsigned short)(u >> 16);
}
__device__ __forceinline__ int read_label(const unsigned int* lab, int is64, int idx) {
    return (int)(is64 ? lab[2 * idx] : lab[idx]);
}
__device__ __forceinline__ void gload_lds16(const void* g, void* l) {
    __builtin_amdgcn_global_load_lds(
        (const __attribute__((address_space(1))) unsigned int*)g,
        (__attribute__((address_space(3))) unsigned int*)l, 16, 0, 0);
}

// ===========================================================================
// ============================ fp8 PATH =====================================
// y8 row layout PERMUTED (8B chunk c at (c&~7)|((c&7)^((row>>1)&7))) so the
// gemm fragment b64 reads are conflict-free with LINEAR global_load_lds.
// ===========================================================================

// K1: compaction with fused dtype detect. pos->[0,P), neg->[512,512+Q).
__global__ __launch_bounds__(512) void k_compact2(const unsigned int* __restrict__ lab,
                                                  int* __restrict__ slotOf,
                                                  int* __restrict__ counts) {
    int b = blockIdx.x, t = threadIdx.x;
    int lnk = t & 63, wv = t >> 6;

    unsigned int odd = (t < 256) ? lab[2 * (b * 256 + t) + 1] : 0u;
    #pragma unroll
    for (int off = 32; off; off >>= 1) odd |= __shfl_xor(odd, off);
    __shared__ unsigned int ow[8];
    if (lnk == 0) ow[wv] = odd;
    __syncthreads();
    unsigned int tot = ow[0] | ow[1] | ow[2] | ow[3] | ow[4] | ow[5] | ow[6] | ow[7];
    int is64 = (tot == 0) ? 1 : 0;

    int lv = read_label(lab, is64, b * NN + t);
    unsigned long long bp = __ballot(lv == 1);
    int prefP = __popcll(bp & ((1ull << lnk) - 1ull));
    __shared__ int wcP[8];
    if (lnk == 0) wcP[wv] = __popcll(bp);
    __syncthreads();
    int baseP = 0, totP = 0;
    #pragma unroll
    for (int w = 0; w < 8; ++w) {
        int c = wcP[w];
        if (w < wv) baseP += c;
        totP += c;
    }
    int baseN = wv * 64 - baseP;
    int prefN = lnk - prefP;
    int slot = (lv == 1) ? (baseP + prefP) : (512 + baseN + prefN);
    slotOf[b * NN + t] = slot;
    if (t == 0) { counts[2 * b] = totP; counts[2 * b + 1] = NN - totP; }
}

// K1b: dense active-tile ticket list.
#define TM 128
#define TN 128
__global__ __launch_bounds__(128) void k_tiles(const int* __restrict__ counts,
                                               int* __restrict__ tileList,
                                               int* __restrict__ nTiles) {
    int b = threadIdx.x;
    int P = counts[2 * b], Q = counts[2 * b + 1];
    int nm = (P > 0) ? (P + TM - 1) / TM : 0;
    int nn = (Q > 0) ? (Q + TN - 1) / TN : 0;
    int cnt = nm * nn;
    __shared__ int pre[128];
    pre[b] = cnt;
    __syncthreads();
    for (int d = 1; d < 128; d <<= 1) {
        int v = (b >= d) ? pre[b - d] : 0;
        __syncthreads();
        pre[b] += v;
        __syncthreads();
    }
    int off = pre[b] - cnt;
    for (int mt = 0; mt < nm; ++mt)
        for (int nt = 0; nt < nn; ++nt)
            tileList[off++] = (b << 8) | (mt << 4) | nt;
    if (b == 127) nTiles[0] = pre[127];
}

// K2: fused L2-normalize + fp32->fp8 + compacting scatter with baked
// per-row chunk permutation.
__global__ __launch_bounds__(256) void k_normcvt(const float* __restrict__ x,
                                                 const int* __restrict__ slotOf,
                                                 unsigned char* __restrict__ y8) {
    int wid = blockIdx.x * 4 + (threadIdx.x >> 6);
    int ln = threadIdx.x & 63;
    const f32x4* src = (const f32x4*)(x + (size_t)wid * DD);
    f32x4 v[4];
    float ss = 0.f;
    #pragma unroll
    for (int j = 0; j < 4; ++j) {
        v[j] = __builtin_nontemporal_load(&src[ln + 64 * j]);
        ss += v[j].x * v[j].x + v[j].y * v[j].y + v[j].z * v[j].z + v[j].w * v[j].w;
    }
    #pragma unroll
    for (int off = 32; off; off >>= 1) ss += __shfl_xor(ss, off);
    float r = rsqrtf(ss);
    int b = wid >> 9;
    int phys = slotOf[wid];
    unsigned char* dst = y8 + ((size_t)b * NR + phys) * DD;
    int w = (phys >> 1) & 7;
    #pragma unroll
    for (int j = 0; j < 4; ++j) {
        int wd = 0;
        wd = __builtin_amdgcn_cvt_pk_fp8_f32(v[j].x * r, v[j].y * r, wd, false);
        wd = __builtin_amdgcn_cvt_pk_fp8_f32(v[j].z * r, v[j].w * r, wd, true);
        int p = ln + 64 * j;
        int c = p >> 1;
        int cp = (c & ~7) | ((c & 7) ^ w);
        *(unsigned int*)&dst[cp * 8 + (p & 1) * 4] = (unsigned int)wd;
    }
}

// K3: balanced partial s_pos from permuted fp8 y.
__global__ __launch_bounds__(256) void k_spos2(const unsigned char* __restrict__ y8,
                                               const int* __restrict__ counts,
                                               float* __restrict__ sposPart) {
    int blk = blockIdx.x;
    int b = blk >> 3, sub = blk & 7;
    int t = threadIdx.x, wv = t >> 6, ln = t & 63;
    int P = counts[2 * b];
    int lo = (sub * P) >> 3, hi = ((sub + 1) * P) >> 3;
    const unsigned char* yb = y8 + (size_t)b * NR * DD;
    int u = 2 * (ln & 3);
    int blockoff = (ln >> 2) * 64;
    float acc[16];
    #pragma unroll
    for (int e = 0; e < 16; ++e) acc[e] = 0.f;
    for (int s = lo + wv; s < hi; s += 4) {
        int w = (s >> 1) & 7;
        const unsigned char* rowp = yb + (size_t)s * DD + blockoff;
        uint2 a8 = *(const uint2*)(rowp + ((u ^ w) * 8));
        uint2 b8 = *(const uint2*)(rowp + (((u + 1) ^ w) * 8));
        unsigned int wa[4] = {a8.x, a8.y, b8.x, b8.y};
        #pragma unroll
        for (int i = 0; i < 4; ++i) {
            acc[4 * i + 0] += __builtin_amdgcn_cvt_f32_fp8(wa[i], 0);
            acc[4 * i + 1] += __builtin_amdgcn_cvt_f32_fp8(wa[i], 1);
            acc[4 * i + 2] += __builtin_amdgcn_cvt_f32_fp8(wa[i], 2);
            acc[4 * i + 3] += __builtin_amdgcn_cvt_f32_fp8(wa[i], 3);
        }
    }
    __shared__ float part[4][1024];
    #pragma unroll
    for (int i = 0; i < 4; ++i)
        *(float4*)&part[wv][16 * ln + 4 * i] =
            make_float4(acc[4 * i], acc[4 * i + 1], acc[4 * i + 2], acc[4 * i + 3]);
    __syncthreads();
    float* outp = sposPart + (size_t)blk * DD;
    #pragma unroll
    for (int g = 0; g < 4; ++g) {
        int c = t + 256 * g;
        outp[c] = part[0][c] + part[1][c] + part[2][c] + part[3][c];
    }
}

// K5: dense-ticket 128x128 fp8 GEMM + fused relu-reduce + MFMA pos_sim.
// *** INSTRUMENTATION ROUND: per-tile body repeated REPS=6x (idempotent) so
// the dispatch surfaces in top-5 with counters. G = (dur_total - 120.1)/5. ***
#define BKG 64
#define REPS 6

__global__ __launch_bounds__(256) void k_gemm2(const unsigned char* __restrict__ y8,
                                               const float* __restrict__ sposPart,
                                               const int* __restrict__ counts,
                                               const int* __restrict__ tileList,
                                               const int* __restrict__ nTiles,
                                               float* __restrict__ partials) {
    int ticket = blockIdx.x;
    if (ticket >= nTiles[0]) return;
    int tid = threadIdx.x;
    int wv = tid >> 6, ln = tid & 63;

    __shared__ unsigned char As[3 * TM * BKG];   // 24KB
    __shared__ unsigned char Bs[3 * TN * BKG];   // 24KB
    __shared__ unsigned int spos8[DD / 4];       // 1KB
    __shared__ float psA[TM];
    __shared__ float red[4];

    int desc = tileList[ticket];
    int b = desc >> 8, mt = (desc >> 4) & 15, nt = desc & 15;
    int P = counts[2 * b], Q = counts[2 * b + 1];

    // stage summed s_pos (fp8) into LDS — once, outside reps
    {
        const float* base = sposPart + (size_t)(b * 8) * DD + 4 * tid;
        float4 s = {0.f, 0.f, 0.f, 0.f};
        #pragma unroll
        for (int p = 0; p < 8; ++p) {
            float4 v = *(const float4*)(base + (size_t)p * DD);
            s.x += v.x; s.y += v.y; s.z += v.z; s.w += v.w;
        }
        int w = 0;
        w = __builtin_amdgcn_cvt_pk_fp8_f32(s.x, s.y, w, false);
        w = __builtin_amdgcn_cvt_pk_fp8_f32(s.z, s.w, w, true);
        spos8[tid] = (unsigned int)w;
    }
    asm volatile("s_waitcnt lgkmcnt(0)" ::: "memory");
    __builtin_amdgcn_sched_barrier(0);

    const unsigned char* yb = y8 + (size_t)b * NR * DD;
    int arow0 = mt * TM;
    int brow0 = 512 + nt * TN;
    int rr = ln >> 2;
    int cbS = (ln & 3) * 16;             // LINEAR staging (swizzle baked in y8)
    int rA[2], rB[2];
    #pragma unroll
    for (int g = 0; g < 2; ++g) {
        int ran = arow0 + wv * 32 + g * 16 + rr;
        rA[g] = (ran > 511) ? 511 : ran;
        int rbn = brow0 + wv * 32 + g * 16 + rr;
        rB[g] = (rbn > NR - 1) ? (NR - 1) : rbn;
    }

#define STAGE(bufsel, kk)                                                      \
    {                                                                          \
        _Pragma("unroll")                                                      \
        for (int g_ = 0; g_ < 2; ++g_) {                                       \
            gload_lds16(yb + (size_t)rA[g_] * DD + (kk) + cbS,                 \
                        &As[(bufsel) * TM * BKG + (wv * 32 + g_ * 16) * BKG]); \
            gload_lds16(yb + (size_t)rB[g_] * DD + (kk) + cbS,                 \
                        &Bs[(bufsel) * TN * BKG + (wv * 32 + g_ * 16) * BKG]); \
        }                                                                      \
    }

    int wr = (wv >> 1) * 64, wc = (wv & 1) * 64;
    int fr = ln & 15;
    int wfr = (fr >> 1) & 7;
    int c0 = ln >> 4;
    bool col0 = (fr == 0);

#define COMPUTE(cur, kbase)                                                    \
    {                                                                          \
        i64f8 af[2][4], bfv[2][4], sx[2];                                      \
        _Pragma("unroll")                                                      \
        for (int ks = 0; ks < 2; ++ks) {                                       \
            int cc = c0 + 4 * ks;                                              \
            int off = (cc ^ wfr) * 8;                                          \
            _Pragma("unroll")                                                  \
            for (int m = 0; m < 4; ++m)                                        \
                af[ks][m] = *(const i64f8*)&As[(cur) * TM * BKG +              \
                                               (wr + m * 16 + fr) * BKG + off];\
            _Pragma("unroll")                                                  \
            for (int n = 0; n < 4; ++n)                                        \
                bfv[ks][n] = *(const i64f8*)&Bs[(cur) * TN * BKG +             \
                                                (wc + n * 16 + fr) * BKG + off];\
            i64f8 sv = *(const i64f8*)&((const unsigned char*)spos8)[(kbase) + \
                                                                     cc * 8];  \
            sx[ks] = col0 ? sv : (i64f8)0;                                     \
        }                                                                      \
        __builtin_amdgcn_s_setprio(1);                                         \
        _Pragma("unroll")                                                      \
        for (int ks = 0; ks < 2; ++ks) {                                       \
            _Pragma("unroll")                                                  \
            for (int m = 0; m < 4; ++m)                                        \
                _Pragma("unroll")                                              \
                for (int n = 0; n < 4; ++n)                                    \
                    acc[m][n] = __builtin_amdgcn_mfma_f32_16x16x32_fp8_fp8(    \
                        af[ks][m], bfv[ks][n], acc[m][n], 0, 0, 0);            \
            _Pragma("unroll")                                                  \
            for (int m = 0; m < 4; ++m)                                        \
                accE[m] = __builtin_amdgcn_mfma_f32_16x16x32_fp8_fp8(          \
                    af[ks][m], sx[ks], accE[m], 0, 0, 0);                      \
        }                                                                      \
        __builtin_amdgcn_s_setprio(0);                                         \
    }

    for (int rep = 0; rep < REPS; ++rep) {
        f32x4 acc[4][4];
        #pragma unroll
        for (int m = 0; m < 4; ++m)
            #pragma unroll
            for (int n = 0; n < 4; ++n)
                acc[m][n] = (f32x4){0.f, 0.f, 0.f, 0.f};
        f32x4 accE[4];
        #pragma unroll
        for (int m = 0; m < 4; ++m) accE[m] = (f32x4){0.f, 0.f, 0.f, 0.f};

        STAGE(0, 0);
        STAGE(1, BKG);
        STAGE(2, 2 * BKG);          // 12 loads in flight

        int cur = 0;
        for (int t = 0; t < 16; ++t) {
            if (t < 14)       asm volatile("s_waitcnt vmcnt(8)" ::: "memory");
            else if (t == 14) asm volatile("s_waitcnt vmcnt(4)" ::: "memory");
            else              asm volatile("s_waitcnt vmcnt(0)" ::: "memory");
            __builtin_amdgcn_s_barrier();
            __builtin_amdgcn_sched_barrier(0);
            COMPUTE(cur, t * BKG);
            __builtin_amdgcn_s_barrier();
            __builtin_amdgcn_sched_barrier(0);
            if (t < 13) STAGE(cur, (t + 3) * BKG);
            cur = (cur == 2) ? 0 : cur + 1;
        }

        float invPm1 = (P > 1) ? 1.0f / (float)(P - 1) : 0.f;
        if (col0 && (wv & 1) == 0) {
            int r0 = (ln >> 4) * 4;
            #pragma unroll
            for (int m = 0; m < 4; ++m)
                #pragma unroll
                for (int q = 0; q < 4; ++q)
                    psA[wr + m * 16 + r0 + q] =
                        (P > 1) ? (accE[m][q] - 1.0f) * invPm1 : 1.0f;
        }
        __syncthreads();

        float lsum = 0.f;
        int irow0 = wr + (ln >> 4) * 4;
        #pragma unroll
        for (int m = 0; m < 4; ++m) {
            #pragma unroll
            for (int n = 0; n < 4; ++n) {
                int j = wc + fr + n * 16;
                bool jok = (nt * TN + j) < Q;
                #pragma unroll
                for (int q = 0; q < 4; ++q) {
                    int i = irow0 + m * 16 + q;
                    float v = fmaxf(acc[m][n][q] - psA[i] + MARGIN, 0.f);
                    bool iok = (mt * TM + i) < P;
                    lsum += (iok && jok) ? v : 0.f;
                }
            }
        }
        #pragma unroll
        for (int off = 32; off; off >>= 1) lsum += __shfl_xor(lsum, off);
        if (ln == 0) red[wv] = lsum;
        __syncthreads();
        if (tid == 0) partials[ticket] = (red[0] + red[1] + red[2] + red[3]) / (float)Q;
        __syncthreads();   // red/psA safe to rewrite next rep
    }
#undef STAGE
#undef COMPUTE
}

// K6: deterministic final reduction over dense tickets.
__global__ __launch_bounds__(256) void k_final(const float* __restrict__ partials,
                                               const int* __restrict__ nTiles,
                                               const int* __restrict__ counts,
                                               float* __restrict__ out) {
    int t = threadIdx.x;
    int A = nTiles[0];
    float s = 0.f;
    for (int i = t; i < A; i += 256) s += partials[i];
    int c = 0;
    for (int b = t; b < BB; b += 256) {
        int P = counts[2 * b], Q = counts[2 * b + 1];
        if (P > 0 && Q > 0) c += P;
    }
    #pragma unroll
    for (int off = 32; off; off >>= 1) {
        s += __shfl_xor(s, off);
        c += __shfl_xor(c, off);
    }
    __shared__ float rs[4];
    __shared__ int ri[4];
    if ((t & 63) == 0) { rs[t >> 6] = s; ri[t >> 6] = c; }
    __syncthreads();
    if (t == 0) {
        float st = rs[0] + rs[1] + rs[2] + rs[3];
        int ct = ri[0] + ri[1] + ri[2] + ri[3];
        out[0] = st / (float)(ct < 1 ? 1 : ct);
    }
}

// ===========================================================================
// ====================== FALLBACK (fp32) PATH ===============================
// ===========================================================================

__global__ __launch_bounds__(256) void k_detect(const unsigned int* __restrict__ lab,
                                                int* __restrict__ flag) {
    int t = threadIdx.x;
    unsigned int acc = 0;
    for (int i = t; i < 32768; i += 256) acc |= lab[2 * i + 1];
    #pragma unroll
    for (int off = 32; off; off >>= 1) acc |= __shfl_xor(acc, off);
    __shared__ unsigned int w[4];
    if ((t & 63) == 0) w[t >> 6] = acc;
    __syncthreads();
    if (t == 0) flag[0] = ((w[0] | w[1] | w[2] | w[3]) == 0) ? 1 : 0;
}

__global__ __launch_bounds__(256) void k_norm_spos(const float* __restrict__ x,
                                                   const unsigned int* __restrict__ lab,
                                                   const int* __restrict__ flag,
                                                   float* __restrict__ rnorm,
                                                   float* __restrict__ sposPart) {
    int blk = blockIdx.x;
    int b = blk >> 2, sub = blk & 3;
    int t = threadIdx.x;
    int m0 = sub * 128;
    __shared__ float rn[128];
    __shared__ int lb[128];
    const float* xb = x + (size_t)b * NN * DD;
    int is64 = flag[0];
    int wv = t >> 6, ln = t & 63;
    for (int r = wv; r < 128; r += 4) {
        const float4* row = (const float4*)(xb + (size_t)(m0 + r) * DD);
        float s = 0.f;
        #pragma unroll
        for (int k = 0; k < 4; ++k) {
            float4 v = row[ln + 64 * k];
            s += v.x * v.x + v.y * v.y + v.z * v.z + v.w * v.w;
        }
        #pragma unroll
        for (int off = 32; off; off >>= 1) s += __shfl_xor(s, off);
        if (ln == 0) {
            float r_ = rsqrtf(s);
            rn[r] = r_;
            rnorm[b * NN + m0 + r] = r_;
        }
    }
    if (t < 128) lb[t] = read_label(lab, is64, b * NN + m0 + t);
    __syncthreads();
    float s0 = 0.f, s1 = 0.f, s2 = 0.f, s3 = 0.f;
    for (int m = 0; m < 128; ++m) {
        if (lb[m] == 1) {
            float rr = rn[m];
            const float* xr = xb + (size_t)(m0 + m) * DD;
            s0 += xr[t] * rr; s1 += xr[t + 256] * rr;
            s2 += xr[t + 512] * rr; s3 += xr[t + 768] * rr;
        }
    }
    float* sp = sposPart + (size_t)blk * DD;
    sp[t] = s0; sp[t + 256] = s1; sp[t + 512] = s2; sp[t + 768] = s3;
}

__global__ __launch_bounds__(512) void k_compact_fb(const unsigned int* __restrict__ lab,
                                                    const int* __restrict__ flag,
                                                    int* __restrict__ posIdx,
                                                    int* __restrict__ negIdx,
                                                    int* __restrict__ counts) {
    int b = blockIdx.x;
    int t = threadIdx.x;
    __shared__ int pidx[NN], nidx[NN];
    __shared__ int cP, cN;
    if (t == 0) { cP = 0; cN = 0; }
    __syncthreads();
    int lv = read_label(lab, flag[0], b * NN + t);
    if (lv == 1)      { int p = atomicAdd(&cP, 1); pidx[p] = t; }
    else if (lv == 0) { int q = atomicAdd(&cN, 1); nidx[q] = t; }
    __syncthreads();
    posIdx[b * NN + t] = (t < cP) ? pidx[t] : 0;
    negIdx[b * NN + t] = (t < cN) ? nidx[t] : 0;
    if (t == 0) { counts[2 * b] = cP; counts[2 * b + 1] = cN; }
}

__global__ __launch_bounds__(256) void k_possim_fb(const float* __restrict__ x,
                                                   const float* __restrict__ rnorm,
                                                   const float* __restrict__ sposPart,
                                                   const int* __restrict__ posIdx,
                                                   const int* __restrict__ counts,
                                                   float* __restrict__ posSimC) {
    int wid = (blockIdx.x * blockDim.x + threadIdx.x) >> 6;
    int ln = threadIdx.x & 63;
    int b = wid >> 9, i = wid & 511;
    int P = counts[2 * b];
    if (i >= P) { if (ln == 0) posSimC[b * NN + i] = 0.f; return; }
    int n = posIdx[b * NN + i];
    const float* xr = x + ((size_t)b * NN + n) * DD;
    const float* sp = sposPart + (size_t)(b * 4) * DD;
    float s = 0.f;
    #pragma unroll
    for (int k = 0; k < 16; ++k) {
        int c = ln + 64 * k;
        float spv = sp[c] + sp[c + DD] + sp[c + 2 * DD] + sp[c + 3 * DD];
        s += xr[c] * spv;
    }
    #pragma unroll
    for (int off = 32; off; off >>= 1) s += __shfl_xor(s, off);
    if (ln == 0) {
        float ps = (P > 1) ? (s * rnorm[b * NN + n] - 1.0f) / (float)(P - 1) : 1.0f;
        posSimC[b * NN + i] = ps;
    }
}

#define LDST 40
#define FTM 128
#define FTN 128
__global__ __launch_bounds__(256) void k_gemm_fb(const float* __restrict__ x,
                                                 const float* __restrict__ rnorm,
                                                 const int* __restrict__ posIdx,
                                                 const int* __restrict__ negIdx,
                                                 const float* __restrict__ posSimC,
                                                 const int* __restrict__ counts,
                                                 float* __restrict__ partials) {
    int blk = blockIdx.x;
    int b = blk >> 4;
    int mt = (blk >> 2) & 3, nt = blk & 3;
    int tid = threadIdx.x;
    int P = counts[2 * b], Q = counts[2 * b + 1];
    if (mt * FTM >= P || nt * FTN >= Q) {
        if (tid == 0) partials[blk] = 0.f;
        return;
    }
    __shared__ unsigned short As[FTM * LDST];
    __shared__ unsigned short Bs[FTN * LDST];
    __shared__ float rnA[FTM], rnB[FTN], psA[FTM];
    __shared__ int gA[FTM], gB[FTN];
    __shared__ float red[4];
    if (tid < FTM) {
        int gi = posIdx[b * NN + mt * FTM + tid];
        gA[tid] = gi;
        rnA[tid] = rnorm[b * NN + gi];
        psA[tid] = posSimC[b * NN + mt * FTM + tid];
    } else {
        int j = tid - FTM;
        int gj = negIdx[b * NN + nt * FTN + j];
        gB[j] = gj;
        rnB[j] = rnorm[b * NN + gj];
    }
    __syncthreads();
    int sr = tid >> 1, sh = tid & 1;
    const float* xb = x + (size_t)b * NN * DD;
    const float* pa = xb + (size_t)gA[sr] * DD + sh * 16;
    const float* pb = xb + (size_t)gB[sr] * DD + sh * 16;
    unsigned short* wa = &As[sr * LDST + sh * 16];
    unsigned short* wb = &Bs[sr * LDST + sh * 16];
    int wv = tid >> 6, ln = tid & 63;
    int wr = (wv >> 1) * 64, wc = (wv & 1) * 64;
    int fr = ln & 15;
    int kh = (ln >> 4) * 8;
    f32x4 acc[4][4];
    #pragma unroll
    for (int m = 0; m < 4; ++m)
        #pragma unroll
        for (int n = 0; n < 4; ++n)
            acc[m][n] = (f32x4){0.f, 0.f, 0.f, 0.f};
    float4 la[4], lbv[4];
    #pragma unroll
    for (int j = 0; j < 4; ++j) {
        la[j]  = *(const float4*)(pa + 4 * j);
        lbv[j] = *(const float4*)(pb + 4 * j);
    }
    for (int k0 = 0; k0 < DD; k0 += 32) {
        ushort8 ua0 = {f2bf(la[0].x), f2bf(la[0].y), f2bf(la[0].z), f2bf(la[0].w),
                       f2bf(la[1].x), f2bf(la[1].y), f2bf(la[1].z), f2bf(la[1].w)};
        ushort8 ua1 = {f2bf(la[2].x), f2bf(la[2].y), f2bf(la[2].z), f2bf(la[2].w),
                       f2bf(la[3].x), f2bf(la[3].y), f2bf(la[3].z), f2bf(la[3].w)};
        ushort8 ub0 = {f2bf(lbv[0].x), f2bf(lbv[0].y), f2bf(lbv[0].z), f2bf(lbv[0].w),
                       f2bf(lbv[1].x), f2bf(lbv[1].y), f2bf(lbv[1].z), f2bf(lbv[1].w)};
        ushort8 ub1 = {f2bf(lbv[2].x), f2bf(lbv[2].y), f2bf(lbv[2].z), f2bf(lbv[2].w),
                       f2bf(lbv[3].x), f2bf(lbv[3].y), f2bf(lbv[3].z), f2bf(lbv[3].w)};
        __syncthreads();
        *(ushort8*)wa = ua0; *(ushort8*)(wa + 8) = ua1;
        *(ushort8*)wb = ub0; *(ushort8*)(wb + 8) = ub1;
        __syncthreads();
        if (k0 + 32 < DD) {
            #pragma unroll
            for (int j = 0; j < 4; ++j) {
                la[j]  = *(const float4*)(pa + k0 + 32 + 4 * j);
                lbv[j] = *(const float4*)(pb + k0 + 32 + 4 * j);
            }
        }
        bf16x8 af[4], bfv[4];
        #pragma unroll
        for (int m = 0; m < 4; ++m)
            af[m] = *(const bf16x8*)&As[(wr + m * 16 + fr) * LDST + kh];
        #pragma unroll
        for (int n = 0; n < 4; ++n)
            bfv[n] = *(const bf16x8*)&Bs[(wc + n * 16 + fr) * LDST + kh];
        #pragma unroll
        for (int m = 0; m < 4; ++m)
            #pragma unroll
            for (int n = 0; n < 4; ++n)
                acc[m][n] = __builtin_amdgcn_mfma_f32_16x16x32_bf16(af[m], bfv[n], acc[m][n], 0, 0, 0);
    }
    float lsum = 0.f;
    int irow0 = wr + (ln >> 4) * 4;
    #pragma unroll
    for (int m = 0; m < 4; ++m) {
        #pragma unroll
        for (int n = 0; n < 4; ++n) {
            int j = wc + fr + n * 16;
            float rbn = rnB[j];
            bool jok = (nt * FTN + j) < Q;
            #pragma unroll
            for (int q = 0; q < 4; ++q) {
                int i = irow0 + m * 16 + q;
                float v = fmaxf(acc[m][n][q] * rnA[i] * rbn - psA[i] + MARGIN, 0.f);
                bool iok = (mt * FTM + i) < P;
                lsum += (iok && jok) ? v : 0.f;
            }
        }
    }
    #pragma unroll
    for (int off = 32; off; off >>= 1) lsum += __shfl_xor(lsum, off);
    if (ln == 0) red[wv] = lsum;
    __syncthreads();
    if (tid == 0) partials[blk] = (red[0] + red[1] + red[2] + red[3]) / (float)Q;
}

__global__ __launch_bounds__(256) void k_final_fb(const float* __restrict__ partials,
                                                  const int* __restrict__ counts,
                                                  float* __restrict__ out) {
    int t = threadIdx.x;
    float s = 0.f;
    for (int i = t; i < BB * 16; i += 256) s += partials[i];
    int c = 0;
    for (int b = t; b < BB; b += 256) {
        int P = counts[2 * b], Q = counts[2 * b + 1];
        if (P > 0 && Q > 0) c += P;
    }
    #pragma unroll
    for (int off = 32; off; off >>= 1) {
        s += __shfl_xor(s, off);
        c += __shfl_xor(c, off);
    }
    __shared__ float rs[4];
    __shared__ int ri[4];
    if ((t & 63) == 0) { rs[t >> 6] = s; ri[t >> 6] = c; }
    __syncthreads();
    if (t == 0) {
        float st = rs[0] + rs[1] + rs[2] + rs[3];
        int ct = ri[0] + ri[1] + ri[2] + ri[3];
        out[0] = st / (float)(ct < 1 ? 1 : ct);
    }
}

// ---------------------------------------------------------------------------
extern "C" void kernel_launch(void* const* d_in, const int* in_sizes, int n_in,
                              void* d_out, int out_size, void* d_ws, size_t ws_size,
                              hipStream_t stream) {
    const float* x = (const float*)d_in[0];
    const unsigned int* lab = (const unsigned int*)d_in[1];
    char* ws = (char*)d_ws;
    float* out = (float*)d_out;

    const size_t Y_BYTES = (size_t)BB * NR * DD;       // 134217728 (fp8, padded)
    const size_t O_SLOT  = Y_BYTES;                    // slotOf: 256KB
    const size_t O_CNT   = O_SLOT + 262144;            // counts: 1KB
    const size_t O_SPOS  = O_CNT + 1024;               // sposPart[BB*8][DD]: 4MB
    const size_t O_PART  = O_SPOS + 4194304;           // partials: 16KB
    const size_t O_TILE  = O_PART + 16384;             // tileList: 8KB
    const size_t O_NT    = O_TILE + 8192;              // nTiles: 64B
    const size_t NEED    = O_NT + 64;

    if (ws_size >= NEED) {
        unsigned char* y8 = (unsigned char*)ws;
        int*   slotOf   = (int*)(ws + O_SLOT);
        int*   counts   = (int*)(ws + O_CNT);
        float* sposPart = (float*)(ws + O_SPOS);
        float* partials = (float*)(ws + O_PART);
        int*   tileList = (int*)(ws + O_TILE);
        int*   nTiles   = (int*)(ws + O_NT);

        k_compact2<<<BB, 512, 0, stream>>>(lab, slotOf, counts);
        k_tiles<<<1, 128, 0, stream>>>(counts, tileList, nTiles);
        k_normcvt<<<16384, 256, 0, stream>>>(x, slotOf, y8);
        k_spos2<<<BB * 8, 256, 0, stream>>>(y8, counts, sposPart);
        k_gemm2<<<2048, 256, 0, stream>>>(y8, sposPart, counts, tileList, nTiles, partials);
        k_final<<<1, 256, 0, stream>>>(partials, nTiles, counts, out);
    } else {
        float* rnorm    = (float*)(ws + 0);
        int*   posIdx   = (int*)(ws + 262144);
        int*   negIdx   = (int*)(ws + 524288);
        float* posSimC  = (float*)(ws + 786432);
        float* sposPart = (float*)(ws + 1048576);
        int*   counts   = (int*)(ws + 3145728);
        float* partials = (float*)(ws + 3146752);
        int*   flag     = (int*)(ws + 3154944);

        k_detect<<<1, 256, 0, stream>>>(lab, flag);
        k_norm_spos<<<BB * 4, 256, 0, stream>>>(x, lab, flag, rnorm, sposPart);
        k_compact_fb<<<BB, 512, 0, stream>>>(lab, flag, posIdx, negIdx, counts);
        k_possim_fb<<<16384, 256, 0, stream>>>(x, rnorm, sposPart, posIdx, counts, posSimC);
        k_gemm_fb<<<BB * 16, 256, 0, stream>>>(x, rnorm, posIdx, negIdx, posSimC, counts, partials);
        k_final_fb<<<1, 256, 0, stream>>>(partials, counts, out);
    }
}

// Round 18
// 116.471 us; speedup vs baseline: 2.9039x; 2.9039x over previous
//
#include <hip/hip_runtime.h>
#include <hip/hip_bf16.h>

#define BB 128
#define NN 512
#define NRB 528   // y8 rows per batch: pos [0,P), neg [Pa, Pa+Q), Pa=(P+15)&~15
#define DD 1024
#define MARGIN 0.3f

typedef __attribute__((ext_vector_type(8))) short bf16x8;
typedef __attribute__((ext_vector_type(4))) float f32x4;
typedef __attribute__((ext_vector_type(8))) unsigned short ushort8;
typedef long i64f8;   // 8 x fp8 (2 VGPR) MFMA operand

__device__ __forceinline__ unsigned short f2bf(float f) {
    unsigned int u = __float_as_uint(f);
    u += 0x7FFFu + ((u >> 16) & 1u);
    return (unsigned short)(u >> 16);
}
__device__ __forceinline__ int read_label(const unsigned int* lab, int is64, int idx) {
    return (int)(is64 ? lab[2 * idx] : lab[idx]);
}
__device__ __forceinline__ void gload_lds16(const void* g, void* l) {
    __builtin_amdgcn_global_load_lds(
        (const __attribute__((address_space(1))) unsigned int*)g,
        (__attribute__((address_space(3))) unsigned int*)l, 16, 0, 0);
}

// ===========================================================================
// ============================ fp8 PATH =====================================
// y8 row layout PERMUTED (8B chunk c at (c&~7)|((c&7)^((row>>1)&7))) so the
// gemm fragment b64 reads are conflict-free with LINEAR global_load_lds.
// COMPACT footprint (~69MB) so y8 stays L3-resident (R17 probe: padded 128MB
// footprint lost L3 -> 97MB HBM refetch per gemm launch).
// ===========================================================================

// K1: compaction with fused dtype detect. pos->[0,P), neg->[Pa,Pa+Q).
__global__ __launch_bounds__(512) void k_compact2(const unsigned int* __restrict__ lab,
                                                  int* __restrict__ slotOf,
                                                  int* __restrict__ counts) {
    int b = blockIdx.x, t = threadIdx.x;
    int lnk = t & 63, wv = t >> 6;

    unsigned int odd = (t < 256) ? lab[2 * (b * 256 + t) + 1] : 0u;
    #pragma unroll
    for (int off = 32; off; off >>= 1) odd |= __shfl_xor(odd, off);
    __shared__ unsigned int ow[8];
    if (lnk == 0) ow[wv] = odd;
    __syncthreads();
    unsigned int tot = ow[0] | ow[1] | ow[2] | ow[3] | ow[4] | ow[5] | ow[6] | ow[7];
    int is64 = (tot == 0) ? 1 : 0;

    int lv = read_label(lab, is64, b * NN + t);
    unsigned long long bp = __ballot(lv == 1);
    int prefP = __popcll(bp & ((1ull << lnk) - 1ull));
    __shared__ int wcP[8];
    if (lnk == 0) wcP[wv] = __popcll(bp);
    __syncthreads();
    int baseP = 0, totP = 0;
    #pragma unroll
    for (int w = 0; w < 8; ++w) {
        int c = wcP[w];
        if (w < wv) baseP += c;
        totP += c;
    }
    int Pa = (totP + 15) & ~15;             // 16-aligned negative base
    int baseN = wv * 64 - baseP;
    int prefN = lnk - prefP;
    int slot = (lv == 1) ? (baseP + prefP) : (Pa + baseN + prefN);
    slotOf[b * NN + t] = slot;
    if (t == 0) { counts[2 * b] = totP; counts[2 * b + 1] = NN - totP; }
}

// K1b: dense active-tile ticket list.
#define TM 128
#define TN 128
__global__ __launch_bounds__(128) void k_tiles(const int* __restrict__ counts,
                                               int* __restrict__ tileList,
                                               int* __restrict__ nTiles) {
    int b = threadIdx.x;
    int P = counts[2 * b], Q = counts[2 * b + 1];
    int nm = (P > 0) ? (P + TM - 1) / TM : 0;
    int nn = (Q > 0) ? (Q + TN - 1) / TN : 0;
    int cnt = nm * nn;
    __shared__ int pre[128];
    pre[b] = cnt;
    __syncthreads();
    for (int d = 1; d < 128; d <<= 1) {
        int v = (b >= d) ? pre[b - d] : 0;
        __syncthreads();
        pre[b] += v;
        __syncthreads();
    }
    int off = pre[b] - cnt;
    for (int mt = 0; mt < nm; ++mt)
        for (int nt = 0; nt < nn; ++nt)
            tileList[off++] = (b << 8) | (mt << 4) | nt;
    if (b == 127) nTiles[0] = pre[127];
}

// K2: fused L2-normalize + fp32->fp8 + compacting scatter with baked
// per-row chunk permutation.
__global__ __launch_bounds__(256) void k_normcvt(const float* __restrict__ x,
                                                 const int* __restrict__ slotOf,
                                                 unsigned char* __restrict__ y8) {
    int wid = blockIdx.x * 4 + (threadIdx.x >> 6);
    int ln = threadIdx.x & 63;
    const f32x4* src = (const f32x4*)(x + (size_t)wid * DD);
    f32x4 v[4];
    float ss = 0.f;
    #pragma unroll
    for (int j = 0; j < 4; ++j) {
        v[j] = __builtin_nontemporal_load(&src[ln + 64 * j]);
        ss += v[j].x * v[j].x + v[j].y * v[j].y + v[j].z * v[j].z + v[j].w * v[j].w;
    }
    #pragma unroll
    for (int off = 32; off; off >>= 1) ss += __shfl_xor(ss, off);
    float r = rsqrtf(ss);
    int b = wid >> 9;
    int phys = slotOf[wid];
    unsigned char* dst = y8 + ((size_t)b * NRB + phys) * DD;
    int w = (phys >> 1) & 7;
    #pragma unroll
    for (int j = 0; j < 4; ++j) {
        int wd = 0;
        wd = __builtin_amdgcn_cvt_pk_fp8_f32(v[j].x * r, v[j].y * r, wd, false);
        wd = __builtin_amdgcn_cvt_pk_fp8_f32(v[j].z * r, v[j].w * r, wd, true);
        int p = ln + 64 * j;
        int c = p >> 1;
        int cp = (c & ~7) | ((c & 7) ^ w);
        *(unsigned int*)&dst[cp * 8 + (p & 1) * 4] = (unsigned int)wd;
    }
}

// K3: balanced partial s_pos from permuted fp8 y.
__global__ __launch_bounds__(256) void k_spos2(const unsigned char* __restrict__ y8,
                                               const int* __restrict__ counts,
                                               float* __restrict__ sposPart) {
    int blk = blockIdx.x;
    int b = blk >> 3, sub = blk & 7;
    int t = threadIdx.x, wv = t >> 6, ln = t & 63;
    int P = counts[2 * b];
    int lo = (sub * P) >> 3, hi = ((sub + 1) * P) >> 3;
    const unsigned char* yb = y8 + (size_t)b * NRB * DD;
    int u = 2 * (ln & 3);
    int blockoff = (ln >> 2) * 64;
    float acc[16];
    #pragma unroll
    for (int e = 0; e < 16; ++e) acc[e] = 0.f;
    for (int s = lo + wv; s < hi; s += 4) {
        int w = (s >> 1) & 7;
        const unsigned char* rowp = yb + (size_t)s * DD + blockoff;
        uint2 a8 = *(const uint2*)(rowp + ((u ^ w) * 8));
        uint2 b8 = *(const uint2*)(rowp + (((u + 1) ^ w) * 8));
        unsigned int wa[4] = {a8.x, a8.y, b8.x, b8.y};
        #pragma unroll
        for (int i = 0; i < 4; ++i) {
            acc[4 * i + 0] += __builtin_amdgcn_cvt_f32_fp8(wa[i], 0);
            acc[4 * i + 1] += __builtin_amdgcn_cvt_f32_fp8(wa[i], 1);
            acc[4 * i + 2] += __builtin_amdgcn_cvt_f32_fp8(wa[i], 2);
            acc[4 * i + 3] += __builtin_amdgcn_cvt_f32_fp8(wa[i], 3);
        }
    }
    __shared__ float part[4][1024];
    #pragma unroll
    for (int i = 0; i < 4; ++i)
        *(float4*)&part[wv][16 * ln + 4 * i] =
            make_float4(acc[4 * i], acc[4 * i + 1], acc[4 * i + 2], acc[4 * i + 3]);
    __syncthreads();
    float* outp = sposPart + (size_t)blk * DD;
    #pragma unroll
    for (int g = 0; g < 4; ++g) {
        int c = t + 256 * g;
        outp[c] = part[0][c] + part[1][c] + part[2][c] + part[3][c];
    }
}

// K5: dense-ticket 128x128 fp8 GEMM + fused relu-reduce + MFMA pos_sim.
// Linear staging (permutation baked); conflict-free b64 reads; compact y8.
#define BKG 64

__global__ __launch_bounds__(256) void k_gemm2(const unsigned char* __restrict__ y8,
                                               const float* __restrict__ sposPart,
                                               const int* __restrict__ counts,
                                               const int* __restrict__ tileList,
                                               const int* __restrict__ nTiles,
                                               float* __restrict__ partials) {
    int ticket = blockIdx.x;
    if (ticket >= nTiles[0]) return;
    int tid = threadIdx.x;
    int wv = tid >> 6, ln = tid & 63;

    __shared__ unsigned char As[3 * TM * BKG];   // 24KB
    __shared__ unsigned char Bs[3 * TN * BKG];   // 24KB
    __shared__ unsigned int spos8[DD / 4];       // 1KB
    __shared__ float psA[TM];
    __shared__ float red[4];

    int desc = tileList[ticket];
    int b = desc >> 8, mt = (desc >> 4) & 15, nt = desc & 15;
    int P = counts[2 * b], Q = counts[2 * b + 1];
    int Pa = (P + 15) & ~15;

    // stage summed s_pos (fp8) into LDS
    {
        const float* base = sposPart + (size_t)(b * 8) * DD + 4 * tid;
        float4 s = {0.f, 0.f, 0.f, 0.f};
        #pragma unroll
        for (int p = 0; p < 8; ++p) {
            float4 v = *(const float4*)(base + (size_t)p * DD);
            s.x += v.x; s.y += v.y; s.z += v.z; s.w += v.w;
        }
        int w = 0;
        w = __builtin_amdgcn_cvt_pk_fp8_f32(s.x, s.y, w, false);
        w = __builtin_amdgcn_cvt_pk_fp8_f32(s.z, s.w, w, true);
        spos8[tid] = (unsigned int)w;
    }
    asm volatile("s_waitcnt lgkmcnt(0)" ::: "memory");
    __builtin_amdgcn_sched_barrier(0);

    const unsigned char* yb = y8 + (size_t)b * NRB * DD;
    int arow0 = mt * TM;                 // 16-aligned
    int brow0 = Pa + nt * TN;            // 16-aligned
    int rr = ln >> 2;
    int cbS = (ln & 3) * 16;             // LINEAR staging (swizzle baked in y8)
    int rA[2], rB[2];
    #pragma unroll
    for (int g = 0; g < 2; ++g) {
        int ran = arow0 + wv * 32 + g * 16 + rr;
        rA[g] = (ran > NRB - 1) ? (NRB - 1) : ran;
        int rbn = brow0 + wv * 32 + g * 16 + rr;
        rB[g] = (rbn > NRB - 1) ? (NRB - 1) : rbn;   // clamp (masked later)
    }

#define STAGE(bufsel, kk)                                                      \
    {                                                                          \
        _Pragma("unroll")                                                      \
        for (int g_ = 0; g_ < 2; ++g_) {                                       \
            gload_lds16(yb + (size_t)rA[g_] * DD + (kk) + cbS,                 \
                        &As[(bufsel) * TM * BKG + (wv * 32 + g_ * 16) * BKG]); \
            gload_lds16(yb + (size_t)rB[g_] * DD + (kk) + cbS,                 \
                        &Bs[(bufsel) * TN * BKG + (wv * 32 + g_ * 16) * BKG]); \
        }                                                                      \
    }

    int wr = (wv >> 1) * 64, wc = (wv & 1) * 64;
    int fr = ln & 15;
    int wfr = (fr >> 1) & 7;             // conflict-free read swizzle
    int c0 = ln >> 4;
    bool col0 = (fr == 0);

    f32x4 acc[4][4];
    #pragma unroll
    for (int m = 0; m < 4; ++m)
        #pragma unroll
        for (int n = 0; n < 4; ++n)
            acc[m][n] = (f32x4){0.f, 0.f, 0.f, 0.f};
    f32x4 accE[4];
    #pragma unroll
    for (int m = 0; m < 4; ++m) accE[m] = (f32x4){0.f, 0.f, 0.f, 0.f};

#define COMPUTE(cur, kbase)                                                    \
    {                                                                          \
        i64f8 af[2][4], bfv[2][4], sx[2];                                      \
        _Pragma("unroll")                                                      \
        for (int ks = 0; ks < 2; ++ks) {                                       \
            int cc = c0 + 4 * ks;                                              \
            int off = (cc ^ wfr) * 8;                                          \
            _Pragma("unroll")                                                  \
            for (int m = 0; m < 4; ++m)                                        \
                af[ks][m] = *(const i64f8*)&As[(cur) * TM * BKG +              \
                                               (wr + m * 16 + fr) * BKG + off];\
            _Pragma("unroll")                                                  \
            for (int n = 0; n < 4; ++n)                                        \
                bfv[ks][n] = *(const i64f8*)&Bs[(cur) * TN * BKG +             \
                                                (wc + n * 16 + fr) * BKG + off];\
            i64f8 sv = *(const i64f8*)&((const unsigned char*)spos8)[(kbase) + \
                                                                     cc * 8];  \
            sx[ks] = col0 ? sv : (i64f8)0;                                     \
        }                                                                      \
        __builtin_amdgcn_s_setprio(1);                                         \
        _Pragma("unroll")                                                      \
        for (int ks = 0; ks < 2; ++ks) {                                       \
            _Pragma("unroll")                                                  \
            for (int m = 0; m < 4; ++m)                                        \
                _Pragma("unroll")                                              \
                for (int n = 0; n < 4; ++n)                                    \
                    acc[m][n] = __builtin_amdgcn_mfma_f32_16x16x32_fp8_fp8(    \
                        af[ks][m], bfv[ks][n], acc[m][n], 0, 0, 0);            \
            _Pragma("unroll")                                                  \
            for (int m = 0; m < 4; ++m)                                        \
                accE[m] = __builtin_amdgcn_mfma_f32_16x16x32_fp8_fp8(          \
                    af[ks][m], sx[ks], accE[m], 0, 0, 0);                      \
        }                                                                      \
        __builtin_amdgcn_s_setprio(0);                                         \
    }

    STAGE(0, 0);
    STAGE(1, BKG);
    STAGE(2, 2 * BKG);          // 12 loads in flight

    int cur = 0;
    for (int t = 0; t < 16; ++t) {
        if (t < 14)       asm volatile("s_waitcnt vmcnt(8)" ::: "memory");
        else if (t == 14) asm volatile("s_waitcnt vmcnt(4)" ::: "memory");
        else              asm volatile("s_waitcnt vmcnt(0)" ::: "memory");
        __builtin_amdgcn_s_barrier();
        __builtin_amdgcn_sched_barrier(0);
        COMPUTE(cur, t * BKG);
        __builtin_amdgcn_s_barrier();
        __builtin_amdgcn_sched_barrier(0);
        if (t < 13) STAGE(cur, (t + 3) * BKG);
        cur = (cur == 2) ? 0 : cur + 1;
    }
#undef STAGE
#undef COMPUTE

    // psA from accE (C layout col=lane&15, row=(lane>>4)*4+q (+m*16));
    // waves 0/1 (2/3) duplicate accE -> even wave writes.
    float invPm1 = (P > 1) ? 1.0f / (float)(P - 1) : 0.f;
    if (col0 && (wv & 1) == 0) {
        int r0 = (ln >> 4) * 4;
        #pragma unroll
        for (int m = 0; m < 4; ++m)
            #pragma unroll
            for (int q = 0; q < 4; ++q)
                psA[wr + m * 16 + r0 + q] =
                    (P > 1) ? (accE[m][q] - 1.0f) * invPm1 : 1.0f;
    }
    __syncthreads();

    float lsum = 0.f;
    int irow0 = wr + (ln >> 4) * 4;
    #pragma unroll
    for (int m = 0; m < 4; ++m) {
        #pragma unroll
        for (int n = 0; n < 4; ++n) {
            int j = wc + fr + n * 16;
            bool jok = (nt * TN + j) < Q;
            #pragma unroll
            for (int q = 0; q < 4; ++q) {
                int i = irow0 + m * 16 + q;
                float v = fmaxf(acc[m][n][q] - psA[i] + MARGIN, 0.f);
                bool iok = (mt * TM + i) < P;
                lsum += (iok && jok) ? v : 0.f;
            }
        }
    }
    #pragma unroll
    for (int off = 32; off; off >>= 1) lsum += __shfl_xor(lsum, off);
    if (ln == 0) red[wv] = lsum;
    __syncthreads();
    if (tid == 0) partials[ticket] = (red[0] + red[1] + red[2] + red[3]) / (float)Q;
}

// K6: deterministic final reduction over dense tickets.
__global__ __launch_bounds__(256) void k_final(const float* __restrict__ partials,
                                               const int* __restrict__ nTiles,
                                               const int* __restrict__ counts,
                                               float* __restrict__ out) {
    int t = threadIdx.x;
    int A = nTiles[0];
    float s = 0.f;
    for (int i = t; i < A; i += 256) s += partials[i];
    int c = 0;
    for (int b = t; b < BB; b += 256) {
        int P = counts[2 * b], Q = counts[2 * b + 1];
        if (P > 0 && Q > 0) c += P;
    }
    #pragma unroll
    for (int off = 32; off; off >>= 1) {
        s += __shfl_xor(s, off);
        c += __shfl_xor(c, off);
    }
    __shared__ float rs[4];
    __shared__ int ri[4];
    if ((t & 63) == 0) { rs[t >> 6] = s; ri[t >> 6] = c; }
    __syncthreads();
    if (t == 0) {
        float st = rs[0] + rs[1] + rs[2] + rs[3];
        int ct = ri[0] + ri[1] + ri[2] + ri[3];
        out[0] = st / (float)(ct < 1 ? 1 : ct);
    }
}

// ===========================================================================
// ====================== FALLBACK (fp32) PATH ===============================
// ===========================================================================

__global__ __launch_bounds__(256) void k_detect(const unsigned int* __restrict__ lab,
                                                int* __restrict__ flag) {
    int t = threadIdx.x;
    unsigned int acc = 0;
    for (int i = t; i < 32768; i += 256) acc |= lab[2 * i + 1];
    #pragma unroll
    for (int off = 32; off; off >>= 1) acc |= __shfl_xor(acc, off);
    __shared__ unsigned int w[4];
    if ((t & 63) == 0) w[t >> 6] = acc;
    __syncthreads();
    if (t == 0) flag[0] = ((w[0] | w[1] | w[2] | w[3]) == 0) ? 1 : 0;
}

__global__ __launch_bounds__(256) void k_norm_spos(const float* __restrict__ x,
                                                   const unsigned int* __restrict__ lab,
                                                   const int* __restrict__ flag,
                                                   float* __restrict__ rnorm,
                                                   float* __restrict__ sposPart) {
    int blk = blockIdx.x;
    int b = blk >> 2, sub = blk & 3;
    int t = threadIdx.x;
    int m0 = sub * 128;
    __shared__ float rn[128];
    __shared__ int lb[128];
    const float* xb = x + (size_t)b * NN * DD;
    int is64 = flag[0];
    int wv = t >> 6, ln = t & 63;
    for (int r = wv; r < 128; r += 4) {
        const float4* row = (const float4*)(xb + (size_t)(m0 + r) * DD);
        float s = 0.f;
        #pragma unroll
        for (int k = 0; k < 4; ++k) {
            float4 v = row[ln + 64 * k];
            s += v.x * v.x + v.y * v.y + v.z * v.z + v.w * v.w;
        }
        #pragma unroll
        for (int off = 32; off; off >>= 1) s += __shfl_xor(s, off);
        if (ln == 0) {
            float r_ = rsqrtf(s);
            rn[r] = r_;
            rnorm[b * NN + m0 + r] = r_;
        }
    }
    if (t < 128) lb[t] = read_label(lab, is64, b * NN + m0 + t);
    __syncthreads();
    float s0 = 0.f, s1 = 0.f, s2 = 0.f, s3 = 0.f;
    for (int m = 0; m < 128; ++m) {
        if (lb[m] == 1) {
            float rr = rn[m];
            const float* xr = xb + (size_t)(m0 + m) * DD;
            s0 += xr[t] * rr; s1 += xr[t + 256] * rr;
            s2 += xr[t + 512] * rr; s3 += xr[t + 768] * rr;
        }
    }
    float* sp = sposPart + (size_t)blk * DD;
    sp[t] = s0; sp[t + 256] = s1; sp[t + 512] = s2; sp[t + 768] = s3;
}

__global__ __launch_bounds__(512) void k_compact_fb(const unsigned int* __restrict__ lab,
                                                    const int* __restrict__ flag,
                                                    int* __restrict__ posIdx,
                                                    int* __restrict__ negIdx,
                                                    int* __restrict__ counts) {
    int b = blockIdx.x;
    int t = threadIdx.x;
    __shared__ int pidx[NN], nidx[NN];
    __shared__ int cP, cN;
    if (t == 0) { cP = 0; cN = 0; }
    __syncthreads();
    int lv = read_label(lab, flag[0], b * NN + t);
    if (lv == 1)      { int p = atomicAdd(&cP, 1); pidx[p] = t; }
    else if (lv == 0) { int q = atomicAdd(&cN, 1); nidx[q] = t; }
    __syncthreads();
    posIdx[b * NN + t] = (t < cP) ? pidx[t] : 0;
    negIdx[b * NN + t] = (t < cN) ? nidx[t] : 0;
    if (t == 0) { counts[2 * b] = cP; counts[2 * b + 1] = cN; }
}

__global__ __launch_bounds__(256) void k_possim_fb(const float* __restrict__ x,
                                                   const float* __restrict__ rnorm,
                                                   const float* __restrict__ sposPart,
                                                   const int* __restrict__ posIdx,
                                                   const int* __restrict__ counts,
                                                   float* __restrict__ posSimC) {
    int wid = (blockIdx.x * blockDim.x + threadIdx.x) >> 6;
    int ln = threadIdx.x & 63;
    int b = wid >> 9, i = wid & 511;
    int P = counts[2 * b];
    if (i >= P) { if (ln == 0) posSimC[b * NN + i] = 0.f; return; }
    int n = posIdx[b * NN + i];
    const float* xr = x + ((size_t)b * NN + n) * DD;
    const float* sp = sposPart + (size_t)(b * 4) * DD;
    float s = 0.f;
    #pragma unroll
    for (int k = 0; k < 16; ++k) {
        int c = ln + 64 * k;
        float spv = sp[c] + sp[c + DD] + sp[c + 2 * DD] + sp[c + 3 * DD];
        s += xr[c] * spv;
    }
    #pragma unroll
    for (int off = 32; off; off >>= 1) s += __shfl_xor(s, off);
    if (ln == 0) {
        float ps = (P > 1) ? (s * rnorm[b * NN + n] - 1.0f) / (float)(P - 1) : 1.0f;
        posSimC[b * NN + i] = ps;
    }
}

#define LDST 40
#define FTM 128
#define FTN 128
__global__ __launch_bounds__(256) void k_gemm_fb(const float* __restrict__ x,
                                                 const float* __restrict__ rnorm,
                                                 const int* __restrict__ posIdx,
                                                 const int* __restrict__ negIdx,
                                                 const float* __restrict__ posSimC,
                                                 const int* __restrict__ counts,
                                                 float* __restrict__ partials) {
    int blk = blockIdx.x;
    int b = blk >> 4;
    int mt = (blk >> 2) & 3, nt = blk & 3;
    int tid = threadIdx.x;
    int P = counts[2 * b], Q = counts[2 * b + 1];
    if (mt * FTM >= P || nt * FTN >= Q) {
        if (tid == 0) partials[blk] = 0.f;
        return;
    }
    __shared__ unsigned short As[FTM * LDST];
    __shared__ unsigned short Bs[FTN * LDST];
    __shared__ float rnA[FTM], rnB[FTN], psA[FTM];
    __shared__ int gA[FTM], gB[FTN];
    __shared__ float red[4];
    if (tid < FTM) {
        int gi = posIdx[b * NN + mt * FTM + tid];
        gA[tid] = gi;
        rnA[tid] = rnorm[b * NN + gi];
        psA[tid] = posSimC[b * NN + mt * FTM + tid];
    } else {
        int j = tid - FTM;
        int gj = negIdx[b * NN + nt * FTN + j];
        gB[j] = gj;
        rnB[j] = rnorm[b * NN + gj];
    }
    __syncthreads();
    int sr = tid >> 1, sh = tid & 1;
    const float* xb = x + (size_t)b * NN * DD;
    const float* pa = xb + (size_t)gA[sr] * DD + sh * 16;
    const float* pb = xb + (size_t)gB[sr] * DD + sh * 16;
    unsigned short* wa = &As[sr * LDST + sh * 16];
    unsigned short* wb = &Bs[sr * LDST + sh * 16];
    int wv = tid >> 6, ln = tid & 63;
    int wr = (wv >> 1) * 64, wc = (wv & 1) * 64;
    int fr = ln & 15;
    int kh = (ln >> 4) * 8;
    f32x4 acc[4][4];
    #pragma unroll
    for (int m = 0; m < 4; ++m)
        #pragma unroll
        for (int n = 0; n < 4; ++n)
            acc[m][n] = (f32x4){0.f, 0.f, 0.f, 0.f};
    float4 la[4], lbv[4];
    #pragma unroll
    for (int j = 0; j < 4; ++j) {
        la[j]  = *(const float4*)(pa + 4 * j);
        lbv[j] = *(const float4*)(pb + 4 * j);
    }
    for (int k0 = 0; k0 < DD; k0 += 32) {
        ushort8 ua0 = {f2bf(la[0].x), f2bf(la[0].y), f2bf(la[0].z), f2bf(la[0].w),
                       f2bf(la[1].x), f2bf(la[1].y), f2bf(la[1].z), f2bf(la[1].w)};
        ushort8 ua1 = {f2bf(la[2].x), f2bf(la[2].y), f2bf(la[2].z), f2bf(la[2].w),
                       f2bf(la[3].x), f2bf(la[3].y), f2bf(la[3].z), f2bf(la[3].w)};
        ushort8 ub0 = {f2bf(lbv[0].x), f2bf(lbv[0].y), f2bf(lbv[0].z), f2bf(lbv[0].w),
                       f2bf(lbv[1].x), f2bf(lbv[1].y), f2bf(lbv[1].z), f2bf(lbv[1].w)};
        ushort8 ub1 = {f2bf(lbv[2].x), f2bf(lbv[2].y), f2bf(lbv[2].z), f2bf(lbv[2].w),
                       f2bf(lbv[3].x), f2bf(lbv[3].y), f2bf(lbv[3].z), f2bf(lbv[3].w)};
        __syncthreads();
        *(ushort8*)wa = ua0; *(ushort8*)(wa + 8) = ua1;
        *(ushort8*)wb = ub0; *(ushort8*)(wb + 8) = ub1;
        __syncthreads();
        if (k0 + 32 < DD) {
            #pragma unroll
            for (int j = 0; j < 4; ++j) {
                la[j]  = *(const float4*)(pa + k0 + 32 + 4 * j);
                lbv[j] = *(const float4*)(pb + k0 + 32 + 4 * j);
            }
        }
        bf16x8 af[4], bfv[4];
        #pragma unroll
        for (int m = 0; m < 4; ++m)
            af[m] = *(const bf16x8*)&As[(wr + m * 16 + fr) * LDST + kh];
        #pragma unroll
        for (int n = 0; n < 4; ++n)
            bfv[n] = *(const bf16x8*)&Bs[(wc + n * 16 + fr) * LDST + kh];
        #pragma unroll
        for (int m = 0; m < 4; ++m)
            #pragma unroll
            for (int n = 0; n < 4; ++n)
                acc[m][n] = __builtin_amdgcn_mfma_f32_16x16x32_bf16(af[m], bfv[n], acc[m][n], 0, 0, 0);
    }
    float lsum = 0.f;
    int irow0 = wr + (ln >> 4) * 4;
    #pragma unroll
    for (int m = 0; m < 4; ++m) {
        #pragma unroll
        for (int n = 0; n < 4; ++n) {
            int j = wc + fr + n * 16;
            float rbn = rnB[j];
            bool jok = (nt * FTN + j) < Q;
            #pragma unroll
            for (int q = 0; q < 4; ++q) {
                int i = irow0 + m * 16 + q;
                float v = fmaxf(acc[m][n][q] * rnA[i] * rbn - psA[i] + MARGIN, 0.f);
                bool iok = (mt * FTM + i) < P;
                lsum += (iok && jok) ? v : 0.f;
            }
        }
    }
    #pragma unroll
    for (int off = 32; off; off >>= 1) lsum += __shfl_xor(lsum, off);
    if (ln == 0) red[wv] = lsum;
    __syncthreads();
    if (tid == 0) partials[blk] = (red[0] + red[1] + red[2] + red[3]) / (float)Q;
}

__global__ __launch_bounds__(256) void k_final_fb(const float* __restrict__ partials,
                                                  const int* __restrict__ counts,
                                                  float* __restrict__ out) {
    int t = threadIdx.x;
    float s = 0.f;
    for (int i = t; i < BB * 16; i += 256) s += partials[i];
    int c = 0;
    for (int b = t; b < BB; b += 256) {
        int P = counts[2 * b], Q = counts[2 * b + 1];
        if (P > 0 && Q > 0) c += P;
    }
    #pragma unroll
    for (int off = 32; off; off >>= 1) {
        s += __shfl_xor(s, off);
        c += __shfl_xor(c, off);
    }
    __shared__ float rs[4];
    __shared__ int ri[4];
    if ((t & 63) == 0) { rs[t >> 6] = s; ri[t >> 6] = c; }
    __syncthreads();
    if (t == 0) {
        float st = rs[0] + rs[1] + rs[2] + rs[3];
        int ct = ri[0] + ri[1] + ri[2] + ri[3];
        out[0] = st / (float)(ct < 1 ? 1 : ct);
    }
}

// ---------------------------------------------------------------------------
extern "C" void kernel_launch(void* const* d_in, const int* in_sizes, int n_in,
                              void* d_out, int out_size, void* d_ws, size_t ws_size,
                              hipStream_t stream) {
    const float* x = (const float*)d_in[0];
    const unsigned int* lab = (const unsigned int*)d_in[1];
    char* ws = (char*)d_ws;
    float* out = (float*)d_out;

    const size_t Y_BYTES = (size_t)BB * NRB * DD;      // 69,206,016 (fp8 compact)
    const size_t O_SLOT  = Y_BYTES;                    // slotOf: 256KB
    const size_t O_CNT   = O_SLOT + 262144;            // counts: 1KB
    const size_t O_SPOS  = O_CNT + 1024;               // sposPart[BB*8][DD]: 4MB
    const size_t O_PART  = O_SPOS + 4194304;           // partials: 16KB
    const size_t O_TILE  = O_PART + 16384;             // tileList: 8KB
    const size_t O_NT    = O_TILE + 8192;              // nTiles: 64B
    const size_t NEED    = O_NT + 64;

    if (ws_size >= NEED) {
        unsigned char* y8 = (unsigned char*)ws;
        int*   slotOf   = (int*)(ws + O_SLOT);
        int*   counts   = (int*)(ws + O_CNT);
        float* sposPart = (float*)(ws + O_SPOS);
        float* partials = (float*)(ws + O_PART);
        int*   tileList = (int*)(ws + O_TILE);
        int*   nTiles   = (int*)(ws + O_NT);

        k_compact2<<<BB, 512, 0, stream>>>(lab, slotOf, counts);
        k_tiles<<<1, 128, 0, stream>>>(counts, tileList, nTiles);
        k_normcvt<<<16384, 256, 0, stream>>>(x, slotOf, y8);
        k_spos2<<<BB * 8, 256, 0, stream>>>(y8, counts, sposPart);
        k_gemm2<<<2048, 256, 0, stream>>>(y8, sposPart, counts, tileList, nTiles, partials);
        k_final<<<1, 256, 0, stream>>>(partials, nTiles, counts, out);
    } else {
        float* rnorm    = (float*)(ws + 0);
        int*   posIdx   = (int*)(ws + 262144);
        int*   negIdx   = (int*)(ws + 524288);
        float* posSimC  = (float*)(ws + 786432);
        float* sposPart = (float*)(ws + 1048576);
        int*   counts   = (int*)(ws + 3145728);
        float* partials = (float*)(ws + 3146752);
        int*   flag     = (int*)(ws + 3154944);

        k_detect<<<1, 256, 0, stream>>>(lab, flag);
        k_norm_spos<<<BB * 4, 256, 0, stream>>>(x, lab, flag, rnorm, sposPart);
        k_compact_fb<<<BB, 512, 0, stream>>>(lab, flag, posIdx, negIdx, counts);
        k_possim_fb<<<16384, 256, 0, stream>>>(x, rnorm, sposPart, posIdx, counts, posSimC);
        k_gemm_fb<<<BB * 16, 256, 0, stream>>>(x, rnorm, posIdx, negIdx, posSimC, counts, partials);
        k_final_fb<<<1, 256, 0, stream>>>(partials, counts, out);
    }
}

// Round 19
// 109.873 us; speedup vs baseline: 3.0783x; 1.0601x over previous
//
#include <hip/hip_runtime.h>
#include <hip/hip_bf16.h>

#define BB 128
#define NN 512
#define NRB 528   // y8 rows per batch: pos [0,P), neg [Pa, Pa+Q), Pa=(P+15)&~15
#define DD 1024
#define MARGIN 0.3f

typedef __attribute__((ext_vector_type(8))) short bf16x8;
typedef __attribute__((ext_vector_type(4))) float f32x4;
typedef __attribute__((ext_vector_type(8))) unsigned short ushort8;
typedef long i64f8;   // 8 x fp8 (2 VGPR) MFMA operand

__device__ __forceinline__ unsigned short f2bf(float f) {
    unsigned int u = __float_as_uint(f);
    u += 0x7FFFu + ((u >> 16) & 1u);
    return (unsigned short)(u >> 16);
}
__device__ __forceinline__ int read_label(const unsigned int* lab, int is64, int idx) {
    return (int)(is64 ? lab[2 * idx] : lab[idx]);
}
__device__ __forceinline__ void gload_lds16(const void* g, void* l) {
    __builtin_amdgcn_global_load_lds(
        (const __attribute__((address_space(1))) unsigned int*)g,
        (__attribute__((address_space(3))) unsigned int*)l, 16, 0, 0);
}

// ===========================================================================
// ============================ fp8 PATH =====================================
// y8 row layout PERMUTED (8B chunk c at (c&~7)|((c&7)^((row>>1)&7))) so the
// gemm fragment b64 reads are conflict-free with LINEAR global_load_lds.
// Compact ~69MB footprint; XCD-chunked ticket swizzle so all tiles of a
// batch run on ONE XCD (panel fetch once per XCD, L2-reuse).
// ===========================================================================

// K1: compaction with fused dtype detect. pos->[0,P), neg->[Pa,Pa+Q).
__global__ __launch_bounds__(512) void k_compact2(const unsigned int* __restrict__ lab,
                                                  int* __restrict__ slotOf,
                                                  int* __restrict__ counts) {
    int b = blockIdx.x, t = threadIdx.x;
    int lnk = t & 63, wv = t >> 6;

    unsigned int odd = (t < 256) ? lab[2 * (b * 256 + t) + 1] : 0u;
    #pragma unroll
    for (int off = 32; off; off >>= 1) odd |= __shfl_xor(odd, off);
    __shared__ unsigned int ow[8];
    if (lnk == 0) ow[wv] = odd;
    __syncthreads();
    unsigned int tot = ow[0] | ow[1] | ow[2] | ow[3] | ow[4] | ow[5] | ow[6] | ow[7];
    int is64 = (tot == 0) ? 1 : 0;

    int lv = read_label(lab, is64, b * NN + t);
    unsigned long long bp = __ballot(lv == 1);
    int prefP = __popcll(bp & ((1ull << lnk) - 1ull));
    __shared__ int wcP[8];
    if (lnk == 0) wcP[wv] = __popcll(bp);
    __syncthreads();
    int baseP = 0, totP = 0;
    #pragma unroll
    for (int w = 0; w < 8; ++w) {
        int c = wcP[w];
        if (w < wv) baseP += c;
        totP += c;
    }
    int Pa = (totP + 15) & ~15;             // 16-aligned negative base
    int baseN = wv * 64 - baseP;
    int prefN = lnk - prefP;
    int slot = (lv == 1) ? (baseP + prefP) : (Pa + baseN + prefN);
    slotOf[b * NN + t] = slot;
    if (t == 0) { counts[2 * b] = totP; counts[2 * b + 1] = NN - totP; }
}

// K1b: dense active-tile ticket list.
#define TM 128
#define TN 128
__global__ __launch_bounds__(128) void k_tiles(const int* __restrict__ counts,
                                               int* __restrict__ tileList,
                                               int* __restrict__ nTiles) {
    int b = threadIdx.x;
    int P = counts[2 * b], Q = counts[2 * b + 1];
    int nm = (P > 0) ? (P + TM - 1) / TM : 0;
    int nn = (Q > 0) ? (Q + TN - 1) / TN : 0;
    int cnt = nm * nn;
    __shared__ int pre[128];
    pre[b] = cnt;
    __syncthreads();
    for (int d = 1; d < 128; d <<= 1) {
        int v = (b >= d) ? pre[b - d] : 0;
        __syncthreads();
        pre[b] += v;
        __syncthreads();
    }
    int off = pre[b] - cnt;
    for (int mt = 0; mt < nm; ++mt)
        for (int nt = 0; nt < nn; ++nt)
            tileList[off++] = (b << 8) | (mt << 4) | nt;
    if (b == 127) nTiles[0] = pre[127];
}

// K2: fused L2-normalize + fp32->fp8 + compacting scatter with baked
// per-row chunk permutation.
__global__ __launch_bounds__(256) void k_normcvt(const float* __restrict__ x,
                                                 const int* __restrict__ slotOf,
                                                 unsigned char* __restrict__ y8) {
    int wid = blockIdx.x * 4 + (threadIdx.x >> 6);
    int ln = threadIdx.x & 63;
    const f32x4* src = (const f32x4*)(x + (size_t)wid * DD);
    f32x4 v[4];
    float ss = 0.f;
    #pragma unroll
    for (int j = 0; j < 4; ++j) {
        v[j] = __builtin_nontemporal_load(&src[ln + 64 * j]);
        ss += v[j].x * v[j].x + v[j].y * v[j].y + v[j].z * v[j].z + v[j].w * v[j].w;
    }
    #pragma unroll
    for (int off = 32; off; off >>= 1) ss += __shfl_xor(ss, off);
    float r = rsqrtf(ss);
    int b = wid >> 9;
    int phys = slotOf[wid];
    unsigned char* dst = y8 + ((size_t)b * NRB + phys) * DD;
    int w = (phys >> 1) & 7;
    #pragma unroll
    for (int j = 0; j < 4; ++j) {
        int wd = 0;
        wd = __builtin_amdgcn_cvt_pk_fp8_f32(v[j].x * r, v[j].y * r, wd, false);
        wd = __builtin_amdgcn_cvt_pk_fp8_f32(v[j].z * r, v[j].w * r, wd, true);
        int p = ln + 64 * j;
        int c = p >> 1;
        int cp = (c & ~7) | ((c & 7) ^ w);
        *(unsigned int*)&dst[cp * 8 + (p & 1) * 4] = (unsigned int)wd;
    }
}

// K3: balanced partial s_pos from permuted fp8 y.
__global__ __launch_bounds__(256) void k_spos2(const unsigned char* __restrict__ y8,
                                               const int* __restrict__ counts,
                                               float* __restrict__ sposPart) {
    int blk = blockIdx.x;
    int b = blk >> 3, sub = blk & 7;
    int t = threadIdx.x, wv = t >> 6, ln = t & 63;
    int P = counts[2 * b];
    int lo = (sub * P) >> 3, hi = ((sub + 1) * P) >> 3;
    const unsigned char* yb = y8 + (size_t)b * NRB * DD;
    int u = 2 * (ln & 3);
    int blockoff = (ln >> 2) * 64;
    float acc[16];
    #pragma unroll
    for (int e = 0; e < 16; ++e) acc[e] = 0.f;
    for (int s = lo + wv; s < hi; s += 4) {
        int w = (s >> 1) & 7;
        const unsigned char* rowp = yb + (size_t)s * DD + blockoff;
        uint2 a8 = *(const uint2*)(rowp + ((u ^ w) * 8));
        uint2 b8 = *(const uint2*)(rowp + (((u + 1) ^ w) * 8));
        unsigned int wa[4] = {a8.x, a8.y, b8.x, b8.y};
        #pragma unroll
        for (int i = 0; i < 4; ++i) {
            acc[4 * i + 0] += __builtin_amdgcn_cvt_f32_fp8(wa[i], 0);
            acc[4 * i + 1] += __builtin_amdgcn_cvt_f32_fp8(wa[i], 1);
            acc[4 * i + 2] += __builtin_amdgcn_cvt_f32_fp8(wa[i], 2);
            acc[4 * i + 3] += __builtin_amdgcn_cvt_f32_fp8(wa[i], 3);
        }
    }
    __shared__ float part[4][1024];
    #pragma unroll
    for (int i = 0; i < 4; ++i)
        *(float4*)&part[wv][16 * ln + 4 * i] =
            make_float4(acc[4 * i], acc[4 * i + 1], acc[4 * i + 2], acc[4 * i + 3]);
    __syncthreads();
    float* outp = sposPart + (size_t)blk * DD;
    #pragma unroll
    for (int g = 0; g < 4; ++g) {
        int c = t + 256 * g;
        outp[c] = part[0][c] + part[1][c] + part[2][c] + part[3][c];
    }
}

// K5: dense-ticket 128x128 fp8 GEMM + fused relu-reduce + MFMA pos_sim.
// XCD-chunked ticket swizzle: blocks on XCD k process a contiguous run of
// tickets (contiguous batches) -> panel fetched once per XCD, L2-reused.
#define BKG 64

__global__ __launch_bounds__(256) void k_gemm2(const unsigned char* __restrict__ y8,
                                               const float* __restrict__ sposPart,
                                               const int* __restrict__ counts,
                                               const int* __restrict__ tileList,
                                               const int* __restrict__ nTiles,
                                               float* __restrict__ partials) {
    int A = nTiles[0];
    int orig = blockIdx.x;
    int xcd = orig & 7, pos = orig >> 3;
    int chunk = (A + 7) >> 3;
    int ticket = xcd * chunk + pos;
    if (pos >= chunk || ticket >= A) return;
    int tid = threadIdx.x;
    int wv = tid >> 6, ln = tid & 63;

    __shared__ unsigned char As[3 * TM * BKG];   // 24KB
    __shared__ unsigned char Bs[3 * TN * BKG];   // 24KB
    __shared__ unsigned int spos8[DD / 4];       // 1KB
    __shared__ float psA[TM];
    __shared__ float red[4];

    int desc = tileList[ticket];
    int b = desc >> 8, mt = (desc >> 4) & 15, nt = desc & 15;
    int P = counts[2 * b], Q = counts[2 * b + 1];
    int Pa = (P + 15) & ~15;

    // stage summed s_pos (fp8) into LDS
    {
        const float* base = sposPart + (size_t)(b * 8) * DD + 4 * tid;
        float4 s = {0.f, 0.f, 0.f, 0.f};
        #pragma unroll
        for (int p = 0; p < 8; ++p) {
            float4 v = *(const float4*)(base + (size_t)p * DD);
            s.x += v.x; s.y += v.y; s.z += v.z; s.w += v.w;
        }
        int w = 0;
        w = __builtin_amdgcn_cvt_pk_fp8_f32(s.x, s.y, w, false);
        w = __builtin_amdgcn_cvt_pk_fp8_f32(s.z, s.w, w, true);
        spos8[tid] = (unsigned int)w;
    }
    asm volatile("s_waitcnt lgkmcnt(0)" ::: "memory");
    __builtin_amdgcn_sched_barrier(0);

    const unsigned char* yb = y8 + (size_t)b * NRB * DD;
    int arow0 = mt * TM;                 // 16-aligned
    int brow0 = Pa + nt * TN;            // 16-aligned
    int rr = ln >> 2;
    int cbS = (ln & 3) * 16;             // LINEAR staging (swizzle baked in y8)
    int rA[2], rB[2];
    #pragma unroll
    for (int g = 0; g < 2; ++g) {
        int ran = arow0 + wv * 32 + g * 16 + rr;
        rA[g] = (ran > NRB - 1) ? (NRB - 1) : ran;
        int rbn = brow0 + wv * 32 + g * 16 + rr;
        rB[g] = (rbn > NRB - 1) ? (NRB - 1) : rbn;   // clamp (masked later)
    }

#define STAGE(bufsel, kk)                                                      \
    {                                                                          \
        _Pragma("unroll")                                                      \
        for (int g_ = 0; g_ < 2; ++g_) {                                       \
            gload_lds16(yb + (size_t)rA[g_] * DD + (kk) + cbS,                 \
                        &As[(bufsel) * TM * BKG + (wv * 32 + g_ * 16) * BKG]); \
            gload_lds16(yb + (size_t)rB[g_] * DD + (kk) + cbS,                 \
                        &Bs[(bufsel) * TN * BKG + (wv * 32 + g_ * 16) * BKG]); \
        }                                                                      \
    }

    int wr = (wv >> 1) * 64, wc = (wv & 1) * 64;
    int fr = ln & 15;
    int wfr = (fr >> 1) & 7;             // conflict-free read swizzle
    int c0 = ln >> 4;
    bool col0 = (fr == 0);

    f32x4 acc[4][4];
    #pragma unroll
    for (int m = 0; m < 4; ++m)
        #pragma unroll
        for (int n = 0; n < 4; ++n)
            acc[m][n] = (f32x4){0.f, 0.f, 0.f, 0.f};
    f32x4 accE[4];
    #pragma unroll
    for (int m = 0; m < 4; ++m) accE[m] = (f32x4){0.f, 0.f, 0.f, 0.f};

#define COMPUTE(cur, kbase)                                                    \
    {                                                                          \
        i64f8 af[2][4], bfv[2][4], sx[2];                                      \
        _Pragma("unroll")                                                      \
        for (int ks = 0; ks < 2; ++ks) {                                       \
            int cc = c0 + 4 * ks;                                              \
            int off = (cc ^ wfr) * 8;                                          \
            _Pragma("unroll")                                                  \
            for (int m = 0; m < 4; ++m)                                        \
                af[ks][m] = *(const i64f8*)&As[(cur) * TM * BKG +              \
                                               (wr + m * 16 + fr) * BKG + off];\
            _Pragma("unroll")                                                  \
            for (int n = 0; n < 4; ++n)                                        \
                bfv[ks][n] = *(const i64f8*)&Bs[(cur) * TN * BKG +             \
                                                (wc + n * 16 + fr) * BKG + off];\
            i64f8 sv = *(const i64f8*)&((const unsigned char*)spos8)[(kbase) + \
                                                                     cc * 8];  \
            sx[ks] = col0 ? sv : (i64f8)0;                                     \
        }                                                                      \
        __builtin_amdgcn_s_setprio(1);                                         \
        _Pragma("unroll")                                                      \
        for (int ks = 0; ks < 2; ++ks) {                                       \
            _Pragma("unroll")                                                  \
            for (int m = 0; m < 4; ++m)                                        \
                _Pragma("unroll")                                              \
                for (int n = 0; n < 4; ++n)                                    \
                    acc[m][n] = __builtin_amdgcn_mfma_f32_16x16x32_fp8_fp8(    \
                        af[ks][m], bfv[ks][n], acc[m][n], 0, 0, 0);            \
            _Pragma("unroll")                                                  \
            for (int m = 0; m < 4; ++m)                                        \
                accE[m] = __builtin_amdgcn_mfma_f32_16x16x32_fp8_fp8(          \
                    af[ks][m], sx[ks], accE[m], 0, 0, 0);                      \
        }                                                                      \
        __builtin_amdgcn_s_setprio(0);                                         \
    }

    STAGE(0, 0);
    STAGE(1, BKG);
    STAGE(2, 2 * BKG);          // 12 loads in flight

    int cur = 0;
    for (int t = 0; t < 16; ++t) {
        if (t < 14)       asm volatile("s_waitcnt vmcnt(8)" ::: "memory");
        else if (t == 14) asm volatile("s_waitcnt vmcnt(4)" ::: "memory");
        else              asm volatile("s_waitcnt vmcnt(0)" ::: "memory");
        __builtin_amdgcn_s_barrier();
        __builtin_amdgcn_sched_barrier(0);
        COMPUTE(cur, t * BKG);
        __builtin_amdgcn_s_barrier();
        __builtin_amdgcn_sched_barrier(0);
        if (t < 13) STAGE(cur, (t + 3) * BKG);
        cur = (cur == 2) ? 0 : cur + 1;
    }
#undef STAGE
#undef COMPUTE

    // psA from accE (C layout col=lane&15, row=(lane>>4)*4+q (+m*16));
    // waves 0/1 (2/3) duplicate accE -> even wave writes.
    float invPm1 = (P > 1) ? 1.0f / (float)(P - 1) : 0.f;
    if (col0 && (wv & 1) == 0) {
        int r0 = (ln >> 4) * 4;
        #pragma unroll
        for (int m = 0; m < 4; ++m)
            #pragma unroll
            for (int q = 0; q < 4; ++q)
                psA[wr + m * 16 + r0 + q] =
                    (P > 1) ? (accE[m][q] - 1.0f) * invPm1 : 1.0f;
    }
    __syncthreads();

    float lsum = 0.f;
    int irow0 = wr + (ln >> 4) * 4;
    #pragma unroll
    for (int m = 0; m < 4; ++m) {
        #pragma unroll
        for (int n = 0; n < 4; ++n) {
            int j = wc + fr + n * 16;
            bool jok = (nt * TN + j) < Q;
            #pragma unroll
            for (int q = 0; q < 4; ++q) {
                int i = irow0 + m * 16 + q;
                float v = fmaxf(acc[m][n][q] - psA[i] + MARGIN, 0.f);
                bool iok = (mt * TM + i) < P;
                lsum += (iok && jok) ? v : 0.f;
            }
        }
    }
    #pragma unroll
    for (int off = 32; off; off >>= 1) lsum += __shfl_xor(lsum, off);
    if (ln == 0) red[wv] = lsum;
    __syncthreads();
    if (tid == 0) partials[ticket] = (red[0] + red[1] + red[2] + red[3]) / (float)Q;
}

// K6: deterministic final reduction over dense tickets.
__global__ __launch_bounds__(256) void k_final(const float* __restrict__ partials,
                                               const int* __restrict__ nTiles,
                                               const int* __restrict__ counts,
                                               float* __restrict__ out) {
    int t = threadIdx.x;
    int A = nTiles[0];
    float s = 0.f;
    for (int i = t; i < A; i += 256) s += partials[i];
    int c = 0;
    for (int b = t; b < BB; b += 256) {
        int P = counts[2 * b], Q = counts[2 * b + 1];
        if (P > 0 && Q > 0) c += P;
    }
    #pragma unroll
    for (int off = 32; off; off >>= 1) {
        s += __shfl_xor(s, off);
        c += __shfl_xor(c, off);
    }
    __shared__ float rs[4];
    __shared__ int ri[4];
    if ((t & 63) == 0) { rs[t >> 6] = s; ri[t >> 6] = c; }
    __syncthreads();
    if (t == 0) {
        float st = rs[0] + rs[1] + rs[2] + rs[3];
        int ct = ri[0] + ri[1] + ri[2] + ri[3];
        out[0] = st / (float)(ct < 1 ? 1 : ct);
    }
}

// ===========================================================================
// ====================== FALLBACK (fp32) PATH ===============================
// ===========================================================================

__global__ __launch_bounds__(256) void k_detect(const unsigned int* __restrict__ lab,
                                                int* __restrict__ flag) {
    int t = threadIdx.x;
    unsigned int acc = 0;
    for (int i = t; i < 32768; i += 256) acc |= lab[2 * i + 1];
    #pragma unroll
    for (int off = 32; off; off >>= 1) acc |= __shfl_xor(acc, off);
    __shared__ unsigned int w[4];
    if ((t & 63) == 0) w[t >> 6] = acc;
    __syncthreads();
    if (t == 0) flag[0] = ((w[0] | w[1] | w[2] | w[3]) == 0) ? 1 : 0;
}

__global__ __launch_bounds__(256) void k_norm_spos(const float* __restrict__ x,
                                                   const unsigned int* __restrict__ lab,
                                                   const int* __restrict__ flag,
                                                   float* __restrict__ rnorm,
                                                   float* __restrict__ sposPart) {
    int blk = blockIdx.x;
    int b = blk >> 2, sub = blk & 3;
    int t = threadIdx.x;
    int m0 = sub * 128;
    __shared__ float rn[128];
    __shared__ int lb[128];
    const float* xb = x + (size_t)b * NN * DD;
    int is64 = flag[0];
    int wv = t >> 6, ln = t & 63;
    for (int r = wv; r < 128; r += 4) {
        const float4* row = (const float4*)(xb + (size_t)(m0 + r) * DD);
        float s = 0.f;
        #pragma unroll
        for (int k = 0; k < 4; ++k) {
            float4 v = row[ln + 64 * k];
            s += v.x * v.x + v.y * v.y + v.z * v.z + v.w * v.w;
        }
        #pragma unroll
        for (int off = 32; off; off >>= 1) s += __shfl_xor(s, off);
        if (ln == 0) {
            float r_ = rsqrtf(s);
            rn[r] = r_;
            rnorm[b * NN + m0 + r] = r_;
        }
    }
    if (t < 128) lb[t] = read_label(lab, is64, b * NN + m0 + t);
    __syncthreads();
    float s0 = 0.f, s1 = 0.f, s2 = 0.f, s3 = 0.f;
    for (int m = 0; m < 128; ++m) {
        if (lb[m] == 1) {
            float rr = rn[m];
            const float* xr = xb + (size_t)(m0 + m) * DD;
            s0 += xr[t] * rr; s1 += xr[t + 256] * rr;
            s2 += xr[t + 512] * rr; s3 += xr[t + 768] * rr;
        }
    }
    float* sp = sposPart + (size_t)blk * DD;
    sp[t] = s0; sp[t + 256] = s1; sp[t + 512] = s2; sp[t + 768] = s3;
}

__global__ __launch_bounds__(512) void k_compact_fb(const unsigned int* __restrict__ lab,
                                                    const int* __restrict__ flag,
                                                    int* __restrict__ posIdx,
                                                    int* __restrict__ negIdx,
                                                    int* __restrict__ counts) {
    int b = blockIdx.x;
    int t = threadIdx.x;
    __shared__ int pidx[NN], nidx[NN];
    __shared__ int cP, cN;
    if (t == 0) { cP = 0; cN = 0; }
    __syncthreads();
    int lv = read_label(lab, flag[0], b * NN + t);
    if (lv == 1)      { int p = atomicAdd(&cP, 1); pidx[p] = t; }
    else if (lv == 0) { int q = atomicAdd(&cN, 1); nidx[q] = t; }
    __syncthreads();
    posIdx[b * NN + t] = (t < cP) ? pidx[t] : 0;
    negIdx[b * NN + t] = (t < cN) ? nidx[t] : 0;
    if (t == 0) { counts[2 * b] = cP; counts[2 * b + 1] = cN; }
}

__global__ __launch_bounds__(256) void k_possim_fb(const float* __restrict__ x,
                                                   const float* __restrict__ rnorm,
                                                   const float* __restrict__ sposPart,
                                                   const int* __restrict__ posIdx,
                                                   const int* __restrict__ counts,
                                                   float* __restrict__ posSimC) {
    int wid = (blockIdx.x * blockDim.x + threadIdx.x) >> 6;
    int ln = threadIdx.x & 63;
    int b = wid >> 9, i = wid & 511;
    int P = counts[2 * b];
    if (i >= P) { if (ln == 0) posSimC[b * NN + i] = 0.f; return; }
    int n = posIdx[b * NN + i];
    const float* xr = x + ((size_t)b * NN + n) * DD;
    const float* sp = sposPart + (size_t)(b * 4) * DD;
    float s = 0.f;
    #pragma unroll
    for (int k = 0; k < 16; ++k) {
        int c = ln + 64 * k;
        float spv = sp[c] + sp[c + DD] + sp[c + 2 * DD] + sp[c + 3 * DD];
        s += xr[c] * spv;
    }
    #pragma unroll
    for (int off = 32; off; off >>= 1) s += __shfl_xor(s, off);
    if (ln == 0) {
        float ps = (P > 1) ? (s * rnorm[b * NN + n] - 1.0f) / (float)(P - 1) : 1.0f;
        posSimC[b * NN + i] = ps;
    }
}

#define LDST 40
#define FTM 128
#define FTN 128
__global__ __launch_bounds__(256) void k_gemm_fb(const float* __restrict__ x,
                                                 const float* __restrict__ rnorm,
                                                 const int* __restrict__ posIdx,
                                                 const int* __restrict__ negIdx,
                                                 const float* __restrict__ posSimC,
                                                 const int* __restrict__ counts,
                                                 float* __restrict__ partials) {
    int blk = blockIdx.x;
    int b = blk >> 4;
    int mt = (blk >> 2) & 3, nt = blk & 3;
    int tid = threadIdx.x;
    int P = counts[2 * b], Q = counts[2 * b + 1];
    if (mt * FTM >= P || nt * FTN >= Q) {
        if (tid == 0) partials[blk] = 0.f;
        return;
    }
    __shared__ unsigned short As[FTM * LDST];
    __shared__ unsigned short Bs[FTN * LDST];
    __shared__ float rnA[FTM], rnB[FTN], psA[FTM];
    __shared__ int gA[FTM], gB[FTN];
    __shared__ float red[4];
    if (tid < FTM) {
        int gi = posIdx[b * NN + mt * FTM + tid];
        gA[tid] = gi;
        rnA[tid] = rnorm[b * NN + gi];
        psA[tid] = posSimC[b * NN + mt * FTM + tid];
    } else {
        int j = tid - FTM;
        int gj = negIdx[b * NN + nt * FTN + j];
        gB[j] = gj;
        rnB[j] = rnorm[b * NN + gj];
    }
    __syncthreads();
    int sr = tid >> 1, sh = tid & 1;
    const float* xb = x + (size_t)b * NN * DD;
    const float* pa = xb + (size_t)gA[sr] * DD + sh * 16;
    const float* pb = xb + (size_t)gB[sr] * DD + sh * 16;
    unsigned short* wa = &As[sr * LDST + sh * 16];
    unsigned short* wb = &Bs[sr * LDST + sh * 16];
    int wv = tid >> 6, ln = tid & 63;
    int wr = (wv >> 1) * 64, wc = (wv & 1) * 64;
    int fr = ln & 15;
    int kh = (ln >> 4) * 8;
    f32x4 acc[4][4];
    #pragma unroll
    for (int m = 0; m < 4; ++m)
        #pragma unroll
        for (int n = 0; n < 4; ++n)
            acc[m][n] = (f32x4){0.f, 0.f, 0.f, 0.f};
    float4 la[4], lbv[4];
    #pragma unroll
    for (int j = 0; j < 4; ++j) {
        la[j]  = *(const float4*)(pa + 4 * j);
        lbv[j] = *(const float4*)(pb + 4 * j);
    }
    for (int k0 = 0; k0 < DD; k0 += 32) {
        ushort8 ua0 = {f2bf(la[0].x), f2bf(la[0].y), f2bf(la[0].z), f2bf(la[0].w),
                       f2bf(la[1].x), f2bf(la[1].y), f2bf(la[1].z), f2bf(la[1].w)};
        ushort8 ua1 = {f2bf(la[2].x), f2bf(la[2].y), f2bf(la[2].z), f2bf(la[2].w),
                       f2bf(la[3].x), f2bf(la[3].y), f2bf(la[3].z), f2bf(la[3].w)};
        ushort8 ub0 = {f2bf(lbv[0].x), f2bf(lbv[0].y), f2bf(lbv[0].z), f2bf(lbv[0].w),
                       f2bf(lbv[1].x), f2bf(lbv[1].y), f2bf(lbv[1].z), f2bf(lbv[1].w)};
        ushort8 ub1 = {f2bf(lbv[2].x), f2bf(lbv[2].y), f2bf(lbv[2].z), f2bf(lbv[2].w),
                       f2bf(lbv[3].x), f2bf(lbv[3].y), f2bf(lbv[3].z), f2bf(lbv[3].w)};
        __syncthreads();
        *(ushort8*)wa = ua0; *(ushort8*)(wa + 8) = ua1;
        *(ushort8*)wb = ub0; *(ushort8*)(wb + 8) = ub1;
        __syncthreads();
        if (k0 + 32 < DD) {
            #pragma unroll
            for (int j = 0; j < 4; ++j) {
                la[j]  = *(const float4*)(pa + k0 + 32 + 4 * j);
                lbv[j] = *(const float4*)(pb + k0 + 32 + 4 * j);
            }
        }
        bf16x8 af[4], bfv[4];
        #pragma unroll
        for (int m = 0; m < 4; ++m)
            af[m] = *(const bf16x8*)&As[(wr + m * 16 + fr) * LDST + kh];
        #pragma unroll
        for (int n = 0; n < 4; ++n)
            bfv[n] = *(const bf16x8*)&Bs[(wc + n * 16 + fr) * LDST + kh];
        #pragma unroll
        for (int m = 0; m < 4; ++m)
            #pragma unroll
            for (int n = 0; n < 4; ++n)
                acc[m][n] = __builtin_amdgcn_mfma_f32_16x16x32_bf16(af[m], bfv[n], acc[m][n], 0, 0, 0);
    }
    float lsum = 0.f;
    int irow0 = wr + (ln >> 4) * 4;
    #pragma unroll
    for (int m = 0; m < 4; ++m) {
        #pragma unroll
        for (int n = 0; n < 4; ++n) {
            int j = wc + fr + n * 16;
            float rbn = rnB[j];
            bool jok = (nt * FTN + j) < Q;
            #pragma unroll
            for (int q = 0; q < 4; ++q) {
                int i = irow0 + m * 16 + q;
                float v = fmaxf(acc[m][n][q] * rnA[i] * rbn - psA[i] + MARGIN, 0.f);
                bool iok = (mt * FTM + i) < P;
                lsum += (iok && jok) ? v : 0.f;
            }
        }
    }
    #pragma unroll
    for (int off = 32; off; off >>= 1) lsum += __shfl_xor(lsum, off);
    if (ln == 0) red[wv] = lsum;
    __syncthreads();
    if (tid == 0) partials[blk] = (red[0] + red[1] + red[2] + red[3]) / (float)Q;
}

__global__ __launch_bounds__(256) void k_final_fb(const float* __restrict__ partials,
                                                  const int* __restrict__ counts,
                                                  float* __restrict__ out) {
    int t = threadIdx.x;
    float s = 0.f;
    for (int i = t; i < BB * 16; i += 256) s += partials[i];
    int c = 0;
    for (int b = t; b < BB; b += 256) {
        int P = counts[2 * b], Q = counts[2 * b + 1];
        if (P > 0 && Q > 0) c += P;
    }
    #pragma unroll
    for (int off = 32; off; off >>= 1) {
        s += __shfl_xor(s, off);
        c += __shfl_xor(c, off);
    }
    __shared__ float rs[4];
    __shared__ int ri[4];
    if ((t & 63) == 0) { rs[t >> 6] = s; ri[t >> 6] = c; }
    __syncthreads();
    if (t == 0) {
        float st = rs[0] + rs[1] + rs[2] + rs[3];
        int ct = ri[0] + ri[1] + ri[2] + ri[3];
        out[0] = st / (float)(ct < 1 ? 1 : ct);
    }
}

// ---------------------------------------------------------------------------
extern "C" void kernel_launch(void* const* d_in, const int* in_sizes, int n_in,
                              void* d_out, int out_size, void* d_ws, size_t ws_size,
                              hipStream_t stream) {
    const float* x = (const float*)d_in[0];
    const unsigned int* lab = (const unsigned int*)d_in[1];
    char* ws = (char*)d_ws;
    float* out = (float*)d_out;

    const size_t Y_BYTES = (size_t)BB * NRB * DD;      // 69,206,016 (fp8 compact)
    const size_t O_SLOT  = Y_BYTES;                    // slotOf: 256KB
    const size_t O_CNT   = O_SLOT + 262144;            // counts: 1KB
    const size_t O_SPOS  = O_CNT + 1024;               // sposPart[BB*8][DD]: 4MB
    const size_t O_PART  = O_SPOS + 4194304;           // partials: 16KB
    const size_t O_TILE  = O_PART + 16384;             // tileList: 8KB
    const size_t O_NT    = O_TILE + 8192;              // nTiles: 64B
    const size_t NEED    = O_NT + 64;

    if (ws_size >= NEED) {
        unsigned char* y8 = (unsigned char*)ws;
        int*   slotOf   = (int*)(ws + O_SLOT);
        int*   counts   = (int*)(ws + O_CNT);
        float* sposPart = (float*)(ws + O_SPOS);
        float* partials = (float*)(ws + O_PART);
        int*   tileList = (int*)(ws + O_TILE);
        int*   nTiles   = (int*)(ws + O_NT);

        k_compact2<<<BB, 512, 0, stream>>>(lab, slotOf, counts);
        k_tiles<<<1, 128, 0, stream>>>(counts, tileList, nTiles);
        k_normcvt<<<16384, 256, 0, stream>>>(x, slotOf, y8);
        k_spos2<<<BB * 8, 256, 0, stream>>>(y8, counts, sposPart);
        k_gemm2<<<2048, 256, 0, stream>>>(y8, sposPart, counts, tileList, nTiles, partials);
        k_final<<<1, 256, 0, stream>>>(partials, nTiles, counts, out);
    } else {
        float* rnorm    = (float*)(ws + 0);
        int*   posIdx   = (int*)(ws + 262144);
        int*   negIdx   = (int*)(ws + 524288);
        float* posSimC  = (float*)(ws + 786432);
        float* sposPart = (float*)(ws + 1048576);
        int*   counts   = (int*)(ws + 3145728);
        float* partials = (float*)(ws + 3146752);
        int*   flag     = (int*)(ws + 3154944);

        k_detect<<<1, 256, 0, stream>>>(lab, flag);
        k_norm_spos<<<BB * 4, 256, 0, stream>>>(x, lab, flag, rnorm, sposPart);
        k_compact_fb<<<BB, 512, 0, stream>>>(lab, flag, posIdx, negIdx, counts);
        k_possim_fb<<<16384, 256, 0, stream>>>(x, rnorm, sposPart, posIdx, counts, posSimC);
        k_gemm_fb<<<BB * 16, 256, 0, stream>>>(x, rnorm, posIdx, negIdx, posSimC, counts, partials);
        k_final_fb<<<1, 256, 0, stream>>>(partials, counts, out);
    }
}